// Round 5
// baseline (1051.546 us; speedup 1.0000x reference)
//
#include <hip/hip_runtime.h>
#include <hip/hip_cooperative_groups.h>
#include <hip/hip_fp16.h>
#include <math.h>

namespace cg = cooperative_groups;

typedef unsigned int u32;
typedef _Float16 h2t __attribute__((ext_vector_type(2)));

// Tree: DEPTH=18, N=2^19-1. Children of i: 2i+1, 2i+2. H=E=64, V=26.
// Exact algebraic folds (unchanged from rounds 1-3):
//   (h1,c1) = lstm_step(lstm_init,0,0); bias2 = W_hh@h1 + b_ih + b_hh;
//   biasS = b_ih + b_hh; M = W_tag@W_comb[:,:64];
//   tag_e2[v] = b_tag + W_tag@(b_comb + W_comb[:,64:]@emb[v]);
//   node_out(h,v) = log_softmax(M@h + tag_e2[v])
// Memos: memo18[26] (leaves), memo17[26^3] (level 17), h2/c2 tables keyed by
// level-17 output id (level-16 step-2).
//
// This round: fp16 weights in LDS (72KB -> 2 blocks/CU), packed-half2
// activations broadcast via readlane + v_dot2_f32_f16 (fp32 accumulate).
// All inter-level buffers are packed half2 (u32 words: (x[2m],x[2m+1])).

// ws offsets in 32-bit words
#define OFF_H1C1   0
#define OFF_BIAS2  128
#define OFF_BIASS  384
#define OFF_M      640
#define OFF_TAGE2  4736
#define OFF_MEMO18 6400
#define OFF_M17P   8064      // u32[17576*32] packed level-17 outputs
#define OFF_H2P    570496    // u32[17576*32] packed h2 table
#define OFF_C2T    1132928   // f32[17576*64] c2 table
#define OFF_BUFA   2257792   // u32[65536*32] packed level buffer (even levels)
#define OFF_BUFB   4354944   // u32[32768*32] packed level buffer (odd levels)
// end 5403520 words = 21.6 MB

__device__ __forceinline__ float sigmf(float x){
  return __fdividef(1.0f, 1.0f + __expf(-x));
}
__device__ __forceinline__ float tanhfast(float x){
  float t = __expf(-2.0f * fabsf(x));
  float r = __fdividef(1.0f - t, 1.0f + t);
  return copysignf(r, x);
}
__device__ __forceinline__ u32 rlu(u32 v, int lane){
  return (u32)__builtin_amdgcn_readlane((int)v, lane);
}
__device__ __forceinline__ float logsoftmax64(float tag){
  float m = tag;
  #pragma unroll
  for (int s = 32; s >= 1; s >>= 1) m = fmaxf(m, __shfl_xor(m, s, 64));
  float ex = __expf(tag - m);
  float sum = ex;
  #pragma unroll
  for (int s = 32; s >= 1; s >>= 1) sum += __shfl_xor(sum, s, 64);
  return tag - m - __logf(sum);
}
__device__ __forceinline__ u32 pk_rn(float a, float b){
  __half2 h = __floats2half2_rn(a, b);
  return __builtin_bit_cast(u32, h);
}
// lane j returns packed (x[j], x[j+1]); valid words live in EVEN lanes.
__device__ __forceinline__ u32 packpair(float x){
  float xn = __shfl_down(x, 1, 64);
  return pk_rn(x, xn);
}
__device__ __forceinline__ void dot2acc(float& acc, u32 w, u32 x){
#if __has_builtin(__builtin_amdgcn_fdot2)
  acc = __builtin_amdgcn_fdot2(__builtin_bit_cast(h2t, w),
                               __builtin_bit_cast(h2t, x), acc, false);
#else
  __half2 wh = __builtin_bit_cast(__half2, w);
  __half2 xh = __builtin_bit_cast(__half2, x);
  float2 wf = __half22float2(wh);
  float2 xf = __half22float2(xh);
  acc = fmaf(wf.x, xf.x, fmaf(wf.y, xf.y, acc));
#endif
}

// XSH=0: packed x gathered per-lane as word (j&31) -> readlane kp.
// XSH=1: packed x self-computed via packpair (even lanes) -> readlane 2*kp.
template<int NT, int XSH>
__device__ __forceinline__ void dotW(const uint4* sW, const u32* XP,
                                     float* A0, float* A1, float* A2, float* A3,
                                     int j)
{
  #pragma unroll 8
  for (int kp = 0; kp < 32; kp++){
    uint4 w = sW[kp*64 + ((j + kp) & 63)];
    #pragma unroll
    for (int t = 0; t < NT; t++){
      u32 xw = rlu(XP[t], kp << XSH);
      dot2acc(A0[t], w.x, xw);
      dot2acc(A1[t], w.y, xw);
      dot2acc(A2[t], w.z, xw);
      dot2acc(A3[t], w.w, xw);
    }
  }
}
template<int NT, int XSH>
__device__ __forceinline__ void dotM(const u32* sMp, const u32* XP,
                                     float* TH, int j)
{
  #pragma unroll 8
  for (int kp = 0; kp < 32; kp++){
    u32 w = sMp[kp*64 + ((j + kp) & 63)];
    #pragma unroll
    for (int t = 0; t < NT; t++)
      dot2acc(TH[t], w, rlu(XP[t], kp << XSH));
  }
}

// ---------------- precompute kernel (1 block, fp32) ----------------
__global__ __launch_bounds__(256) void k_pre(
    const float* __restrict__ emb,
    const float* __restrict__ W_ih, const float* __restrict__ W_hh,
    const float* __restrict__ b_ih, const float* __restrict__ b_hh,
    const float* __restrict__ W_comb, const float* __restrict__ b_comb,
    const float* __restrict__ W_tag, const float* __restrict__ b_tag,
    const float* __restrict__ lstm_init,
    float* __restrict__ ws)
{
  __shared__ float sWt[4096];
  __shared__ float sWc[8192];
  __shared__ float sg[256];
  __shared__ float sh1[64];
  __shared__ float sceT[64*32];
  __shared__ float sM[4096];
  __shared__ float ste[26*64];
  __shared__ float sth[64];
  int t = threadIdx.x;

  for (int idx = t; idx < 4096; idx += 256) sWt[idx] = W_tag[idx];
  for (int idx = t; idx < 8192; idx += 256) sWc[idx] = W_comb[idx];

  float bsum = b_ih[t] + b_hh[t];
  ws[OFF_BIASS + t] = bsum;
  {
    float acc = bsum;
    for (int k = 0; k < 64; k++) acc = fmaf(W_ih[t*64 + k], lstm_init[k], acc);
    sg[t] = acc;
  }
  __syncthreads();

  if (t < 64){
    float ii = sigmf(sg[t]);
    float gg = tanhfast(sg[128 + t]);
    float oo = sigmf(sg[192 + t]);
    float c = ii * gg;
    float h = oo * tanhfast(c);
    sh1[t] = h;
    ws[OFF_H1C1 + t] = h;
    ws[OFF_H1C1 + 64 + t] = c;
  }
  __syncthreads();

  {
    float acc = bsum;
    for (int k = 0; k < 64; k++) acc = fmaf(W_hh[t*64 + k], sh1[k], acc);
    ws[OFF_BIAS2 + t] = acc;
  }
  for (int idx = t; idx < 26*64; idx += 256){
    int jj = idx / 26, v = idx - jj*26;
    float acc = b_comb[jj];
    for (int e = 0; e < 64; e++) acc = fmaf(sWc[jj*128 + 64 + e], emb[v*64 + e], acc);
    sceT[jj*32 + v] = acc;
  }
  for (int idx = t; idx < 4096; idx += 256){
    int jj = idx >> 6, kk = idx & 63;
    float acc = 0.f;
    for (int m = 0; m < 64; m++) acc = fmaf(sWt[jj*64 + m], sWc[m*128 + kk], acc);
    sM[idx] = acc;
    ws[OFF_M + idx] = acc;
  }
  __syncthreads();
  for (int idx = t; idx < 26*64; idx += 256){
    int jj = idx / 26, v = idx - jj*26;
    float acc = b_tag[jj];
    for (int k = 0; k < 64; k++) acc = fmaf(sWt[jj*64 + k], sceT[k*32 + v], acc);
    ws[OFF_TAGE2 + v*64 + jj] = acc;
    ste[v*64 + jj] = acc;
  }
  if (t < 64){
    float acc = 0.f;
    for (int k = 0; k < 64; k++) acc = fmaf(sM[t*64 + k], sh1[k], acc);
    sth[t] = acc;
  }
  __syncthreads();
  int w = t >> 6, j = t & 63;
  for (int v = w; v < 26; v += 4){
    float tag = sth[j] + ste[v*64 + j];
    ws[OFF_MEMO18 + v*64 + j] = logsoftmax64(tag);
  }
}

// ---------------- the cooperative everything-kernel ----------------
__global__ __launch_bounds__(512, 4) void k_main(
    const int* __restrict__ ids,
    const float* __restrict__ W_ih, const float* __restrict__ W_hh,
    float* __restrict__ ws, float* __restrict__ out)
{
  // fp16 weight staging: for k-pair kp, slot s=(j+kp)&63:
  //   sWi4[kp*64+s] = 4 gates x half2(W[g*64+j][2kp], W[g*64+j][2kp+1])
  // reads are 16B/lane contiguous across j -> conflict-free b128.
  __shared__ uint4 sWi4[2048];   // 32 KB
  __shared__ uint4 sWh4[2048];   // 32 KB
  __shared__ u32   sMp[2048];    //  8 KB   total 72 KB -> 2 blocks/CU
  u32* wsu = (u32*)ws;

  for (int idx = threadIdx.x; idx < 2048; idx += blockDim.x){
    int kp = idx >> 6, j = idx & 63;
    int slot = kp*64 + ((j + kp) & 63);
    uint4 wi, wh;
    wi.x = pk_rn(W_ih[(      j)*64 + 2*kp], W_ih[(      j)*64 + 2*kp + 1]);
    wi.y = pk_rn(W_ih[( 64 + j)*64 + 2*kp], W_ih[( 64 + j)*64 + 2*kp + 1]);
    wi.z = pk_rn(W_ih[(128 + j)*64 + 2*kp], W_ih[(128 + j)*64 + 2*kp + 1]);
    wi.w = pk_rn(W_ih[(192 + j)*64 + 2*kp], W_ih[(192 + j)*64 + 2*kp + 1]);
    wh.x = pk_rn(W_hh[(      j)*64 + 2*kp], W_hh[(      j)*64 + 2*kp + 1]);
    wh.y = pk_rn(W_hh[( 64 + j)*64 + 2*kp], W_hh[( 64 + j)*64 + 2*kp + 1]);
    wh.z = pk_rn(W_hh[(128 + j)*64 + 2*kp], W_hh[(128 + j)*64 + 2*kp + 1]);
    wh.w = pk_rn(W_hh[(192 + j)*64 + 2*kp], W_hh[(192 + j)*64 + 2*kp + 1]);
    sWi4[slot] = wi;
    sWh4[slot] = wh;
    sMp[slot]  = pk_rn(ws[OFF_M + j*64 + 2*kp], ws[OFF_M + j*64 + 2*kp + 1]);
  }
  __syncthreads();

  cg::grid_group grid = cg::this_grid();
  int wv = threadIdx.x >> 6, j = threadIdx.x & 63;
  int nw = gridDim.x * 8;
  int gw = blockIdx.x * 8 + wv;
  int j31 = j & 31;

  float c1  = ws[OFF_H1C1 + 64 + j];
  float b20 = ws[OFF_BIAS2 + j],       b21 = ws[OFF_BIAS2 + 64 + j];
  float b22 = ws[OFF_BIAS2 + 128 + j], b23 = ws[OFF_BIAS2 + 192 + j];
  float bs0 = ws[OFF_BIASS + j],       bs1 = ws[OFF_BIASS + 64 + j];
  float bs2 = ws[OFF_BIASS + 128 + j], bs3 = ws[OFF_BIASS + 192 + j];

  // ---- phase A: memo17 over 676 (lid,rid) pairs, 1 node/wave ----
  if (gw < 676){
    int lid = gw / 26, rid = gw - lid*26;
    u32 LP[1] = { packpair(ws[OFF_MEMO18 + lid*64 + j]) };
    u32 RP[1] = { packpair(ws[OFF_MEMO18 + rid*64 + j]) };
    float A0[1] = {b20}, A1[1] = {b21}, A2[1] = {b22}, A3[1] = {b23};
    dotW<1,1>(sWi4, LP, A0, A1, A2, A3, j);
    float c2 = sigmf(A1[0])*c1 + sigmf(A0[0])*tanhfast(A2[0]);
    float h2 = sigmf(A3[0])*tanhfast(c2);
    u32 HP[1] = { packpair(h2) };
    A0[0] = bs0; A1[0] = bs1; A2[0] = bs2; A3[0] = bs3;
    dotW<1,1>(sWi4, RP, A0, A1, A2, A3, j);
    dotW<1,1>(sWh4, HP, A0, A1, A2, A3, j);
    float c3 = sigmf(A1[0])*c2 + sigmf(A0[0])*tanhfast(A2[0]);
    float h3 = sigmf(A3[0])*tanhfast(c3);
    u32 H3P[1] = { packpair(h3) };
    float TH[1] = {0.f};
    dotM<1,1>(sMp, H3P, TH, j);
    for (int iid = 0; iid < 26; iid++){
      float tag = TH[0] + ws[OFF_TAGE2 + iid*64 + j];
      u32 pk = packpair(logsoftmax64(tag));
      if (!(j & 1)) wsu[OFF_M17P + (gw*26 + iid)*32 + (j >> 1)] = pk;
    }
  }
  grid.sync();

  // ---- phase B: h2/c2 tables over 17576 keys, 8 keys/wave ----
  for (int key0 = gw*8; key0 < 17576; key0 += nw*8){
    u32 XP[8]; float A0[8], A1[8], A2[8], A3[8];
    #pragma unroll
    for (int t = 0; t < 8; t++){
      int kc = key0 + t; if (kc > 17575) kc = 17575;
      XP[t] = wsu[OFF_M17P + kc*32 + j31];
      A0[t] = b20; A1[t] = b21; A2[t] = b22; A3[t] = b23;
    }
    dotW<8,0>(sWi4, XP, A0, A1, A2, A3, j);
    #pragma unroll
    for (int t = 0; t < 8; t++){
      int key = key0 + t;
      float c2 = sigmf(A1[t])*c1 + sigmf(A0[t])*tanhfast(A2[t]);
      float h2 = sigmf(A3[t])*tanhfast(c2);
      u32 pk = packpair(h2);
      if (key < 17576){
        ws[OFF_C2T + key*64 + j] = c2;
        if (!(j & 1)) wsu[OFF_H2P + key*32 + (j >> 1)] = pk;
      }
    }
  }
  grid.sync();

  // ---- phase C: level 16 (65536 nodes): gather h2/c2/R by key, step 3 ----
  for (int i0 = gw*8; i0 < 65536; i0 += nw*8){
    u32 RP[8], HP[8]; float C2v[8], A0[8], A1[8], A2[8], A3[8]; int idv[8];
    #pragma unroll
    for (int t = 0; t < 8; t++){
      int i = i0 + t;
      int m0 = 2*i, m1 = 2*i + 1;
      int kL = (ids[262143 + 2*m0]*26 + ids[262143 + 2*m0 + 1])*26 + ids[131071 + m0];
      int kR = (ids[262143 + 2*m1]*26 + ids[262143 + 2*m1 + 1])*26 + ids[131071 + m1];
      idv[t] = ids[65535 + i];
      RP[t]  = wsu[OFF_M17P + kR*32 + j31];
      HP[t]  = wsu[OFF_H2P  + kL*32 + j31];
      C2v[t] = ws[OFF_C2T + kL*64 + j];
      A0[t] = bs0; A1[t] = bs1; A2[t] = bs2; A3[t] = bs3;
    }
    dotW<8,0>(sWi4, RP, A0, A1, A2, A3, j);
    dotW<8,0>(sWh4, HP, A0, A1, A2, A3, j);
    u32 H3P[8];
    #pragma unroll
    for (int t = 0; t < 8; t++){
      float c3 = sigmf(A1[t])*C2v[t] + sigmf(A0[t])*tanhfast(A2[t]);
      H3P[t] = packpair(sigmf(A3[t])*tanhfast(c3));
    }
    float TH[8] = {0.f,0.f,0.f,0.f,0.f,0.f,0.f,0.f};
    dotM<8,1>(sMp, H3P, TH, j);
    #pragma unroll
    for (int t = 0; t < 8; t++){
      float tag = TH[t] + ws[OFF_TAGE2 + idv[t]*64 + j];
      u32 pk = packpair(logsoftmax64(tag));
      if (!(j & 1)) wsu[OFF_BUFA + (i0 + t)*32 + (j >> 1)] = pk;
    }
  }
  grid.sync();

  // ---- phase D: levels 15..0; levels <=6 run in block 0 only ----
  for (int l = 15; l >= 0; --l){
    int B = 1 << l;
    bool tail = (B <= 64);
    if (tail && blockIdx.x != 0) return;
    const u32* prevp = wsu + ((l & 1) ? OFF_BUFA : OFF_BUFB);
    u32*       curp  = wsu + ((l & 1) ? OFF_BUFB : OFF_BUFA);
    int start  = tail ? wv*8 : gw*8;
    int stride = tail ? 64   : nw*8;

    for (int i0 = start; i0 < B; i0 += stride){
      u32 LP[8], RP[8]; float A0[8], A1[8], A2[8], A3[8];
      #pragma unroll
      for (int t = 0; t < 8; t++){
        int i = i0 + t; int ic = (i < B) ? i : 0;
        LP[t] = prevp[(2*ic)*32 + j31];
        RP[t] = prevp[(2*ic + 1)*32 + j31];
        A0[t] = b20; A1[t] = b21; A2[t] = b22; A3[t] = b23;
      }
      dotW<8,0>(sWi4, LP, A0, A1, A2, A3, j);
      float C2v[8]; u32 HP[8];
      #pragma unroll
      for (int t = 0; t < 8; t++){
        float c2 = sigmf(A1[t])*c1 + sigmf(A0[t])*tanhfast(A2[t]);
        float h2 = sigmf(A3[t])*tanhfast(c2);
        C2v[t] = c2; HP[t] = packpair(h2);
        A0[t] = bs0; A1[t] = bs1; A2[t] = bs2; A3[t] = bs3;
      }
      dotW<8,0>(sWi4, RP, A0, A1, A2, A3, j);
      dotW<8,1>(sWh4, HP, A0, A1, A2, A3, j);
      u32 H3P[8];
      #pragma unroll
      for (int t = 0; t < 8; t++){
        float c3 = sigmf(A1[t])*C2v[t] + sigmf(A0[t])*tanhfast(A2[t]);
        H3P[t] = packpair(sigmf(A3[t])*tanhfast(c3));
      }
      float TH[8] = {0.f,0.f,0.f,0.f,0.f,0.f,0.f,0.f};
      dotM<8,1>(sMp, H3P, TH, j);
      #pragma unroll
      for (int t = 0; t < 8; t++){
        int i = i0 + t; bool ok = (i < B);
        int id = ids[(B - 1) + (ok ? i : 0)];
        float tag = TH[t] + ws[OFF_TAGE2 + id*64 + j];
        float v = logsoftmax64(tag);
        u32 pk = packpair(v);
        if (l == 0){
          if (ok) out[j] = v;            // root: fp32 log-probs to d_out
        } else if (ok && !(j & 1)){
          curp[i*32 + (j >> 1)] = pk;
        }
      }
    }
    if (tail) __syncthreads(); else grid.sync();
  }
}

extern "C" void kernel_launch(void* const* d_in, const int* in_sizes, int n_in,
                              void* d_out, int out_size, void* d_ws, size_t ws_size,
                              hipStream_t stream)
{
  (void)in_sizes; (void)n_in; (void)out_size; (void)ws_size;
  const int*   ids    = (const int*)  d_in[0];
  const float* emb    = (const float*)d_in[1];
  const float* W_ih   = (const float*)d_in[2];
  const float* W_hh   = (const float*)d_in[3];
  const float* b_ih   = (const float*)d_in[4];
  const float* b_hh   = (const float*)d_in[5];
  const float* W_comb = (const float*)d_in[6];
  const float* b_comb = (const float*)d_in[7];
  const float* W_tag  = (const float*)d_in[8];
  const float* b_tag  = (const float*)d_in[9];
  const float* linit  = (const float*)d_in[10];
  float* ws  = (float*)d_ws;
  float* out = (float*)d_out;

  k_pre<<<1, 256, 0, stream>>>(emb, W_ih, W_hh, b_ih, b_hh,
                               W_comb, b_comb, W_tag, b_tag, linit, ws);

  int maxb = 1;
  if (hipOccupancyMaxActiveBlocksPerMultiprocessor(&maxb, (const void*)k_main,
                                                   512, 0) != hipSuccess || maxb < 1)
    maxb = 1;
  int grid = maxb * 256; if (grid > 512) grid = 512;

  void* ka[5];
  ka[0] = (void*)&ids;  ka[1] = (void*)&W_ih; ka[2] = (void*)&W_hh;
  ka[3] = (void*)&ws;   ka[4] = (void*)&out;
  (void)hipLaunchCooperativeKernel((const void*)k_main, dim3(grid), dim3(512),
                                   ka, 0, stream);
}

// Round 6
// 856.589 us; speedup vs baseline: 1.2276x; 1.2276x over previous
//
#include <hip/hip_runtime.h>
#include <hip/hip_cooperative_groups.h>
#include <hip/hip_fp16.h>
#include <math.h>

namespace cg = cooperative_groups;

typedef unsigned int u32;
typedef _Float16 h2t __attribute__((ext_vector_type(2)));

// Tree: DEPTH=18, N=2^19-1. Children of i: 2i+1, 2i+2. H=E=64, V=26.
// Exact algebraic folds (unchanged from rounds 1-3):
//   (h1,c1) = lstm_step(lstm_init,0,0); bias2 = W_hh@h1 + b_ih + b_hh;
//   biasS = b_ih + b_hh; M = W_tag@W_comb[:,:64];
//   tag_e2[v] = b_tag + W_tag@(b_comb + W_comb[:,64:]@emb[v]);
//   node_out(h,v) = log_softmax(M@h + tag_e2[v])
// Memos: memo18[26] (leaves), memo17[26^3] (level 17), h2/c2 tables keyed by
// level-17 output id (level-16 step-2).
//
// Round 6 fix: __launch_bounds__(512,2) (was (512,4)). The 4-block request
// capped VGPRs at 64 -> scratch spills (VALUBusy 15%, WRITE_SIZE 47MB).
// LDS (72KB) limits us to 2 blocks/CU regardless, so min-waves=2 restores
// the 128-VGPR budget at identical occupancy.

// ws offsets in 32-bit words
#define OFF_H1C1   0
#define OFF_BIAS2  128
#define OFF_BIASS  384
#define OFF_M      640
#define OFF_TAGE2  4736
#define OFF_MEMO18 6400
#define OFF_M17P   8064      // u32[17576*32] packed level-17 outputs
#define OFF_H2P    570496    // u32[17576*32] packed h2 table
#define OFF_C2T    1132928   // f32[17576*64] c2 table
#define OFF_BUFA   2257792   // u32[65536*32] packed level buffer (even levels)
#define OFF_BUFB   4354944   // u32[32768*32] packed level buffer (odd levels)
// end 5403520 words = 21.6 MB

__device__ __forceinline__ float sigmf(float x){
  return __fdividef(1.0f, 1.0f + __expf(-x));
}
__device__ __forceinline__ float tanhfast(float x){
  float t = __expf(-2.0f * fabsf(x));
  float r = __fdividef(1.0f - t, 1.0f + t);
  return copysignf(r, x);
}
__device__ __forceinline__ u32 rlu(u32 v, int lane){
  return (u32)__builtin_amdgcn_readlane((int)v, lane);
}
__device__ __forceinline__ float logsoftmax64(float tag){
  float m = tag;
  #pragma unroll
  for (int s = 32; s >= 1; s >>= 1) m = fmaxf(m, __shfl_xor(m, s, 64));
  float ex = __expf(tag - m);
  float sum = ex;
  #pragma unroll
  for (int s = 32; s >= 1; s >>= 1) sum += __shfl_xor(sum, s, 64);
  return tag - m - __logf(sum);
}
__device__ __forceinline__ u32 pk_rn(float a, float b){
  __half2 h = __floats2half2_rn(a, b);
  return __builtin_bit_cast(u32, h);
}
// lane j returns packed (x[j], x[j+1]); valid words live in EVEN lanes.
__device__ __forceinline__ u32 packpair(float x){
  float xn = __shfl_down(x, 1, 64);
  return pk_rn(x, xn);
}
__device__ __forceinline__ void dot2acc(float& acc, u32 w, u32 x){
#if __has_builtin(__builtin_amdgcn_fdot2)
  acc = __builtin_amdgcn_fdot2(__builtin_bit_cast(h2t, w),
                               __builtin_bit_cast(h2t, x), acc, false);
#else
  __half2 wh = __builtin_bit_cast(__half2, w);
  __half2 xh = __builtin_bit_cast(__half2, x);
  float2 wf = __half22float2(wh);
  float2 xf = __half22float2(xh);
  acc = fmaf(wf.x, xf.x, fmaf(wf.y, xf.y, acc));
#endif
}

// XSH=0: packed x gathered per-lane as word (j&31) -> readlane kp.
// XSH=1: packed x self-computed via packpair (even lanes) -> readlane 2*kp.
template<int NT, int XSH>
__device__ __forceinline__ void dotW(const uint4* sW, const u32* XP,
                                     float* A0, float* A1, float* A2, float* A3,
                                     int j)
{
  #pragma unroll 8
  for (int kp = 0; kp < 32; kp++){
    uint4 w = sW[kp*64 + ((j + kp) & 63)];
    #pragma unroll
    for (int t = 0; t < NT; t++){
      u32 xw = rlu(XP[t], kp << XSH);
      dot2acc(A0[t], w.x, xw);
      dot2acc(A1[t], w.y, xw);
      dot2acc(A2[t], w.z, xw);
      dot2acc(A3[t], w.w, xw);
    }
  }
}
template<int NT, int XSH>
__device__ __forceinline__ void dotM(const u32* sMp, const u32* XP,
                                     float* TH, int j)
{
  #pragma unroll 8
  for (int kp = 0; kp < 32; kp++){
    u32 w = sMp[kp*64 + ((j + kp) & 63)];
    #pragma unroll
    for (int t = 0; t < NT; t++)
      dot2acc(TH[t], w, rlu(XP[t], kp << XSH));
  }
}

// ---------------- precompute kernel (1 block, fp32) ----------------
__global__ __launch_bounds__(256) void k_pre(
    const float* __restrict__ emb,
    const float* __restrict__ W_ih, const float* __restrict__ W_hh,
    const float* __restrict__ b_ih, const float* __restrict__ b_hh,
    const float* __restrict__ W_comb, const float* __restrict__ b_comb,
    const float* __restrict__ W_tag, const float* __restrict__ b_tag,
    const float* __restrict__ lstm_init,
    float* __restrict__ ws)
{
  __shared__ float sWt[4096];
  __shared__ float sWc[8192];
  __shared__ float sg[256];
  __shared__ float sh1[64];
  __shared__ float sceT[64*32];
  __shared__ float sM[4096];
  __shared__ float ste[26*64];
  __shared__ float sth[64];
  int t = threadIdx.x;

  for (int idx = t; idx < 4096; idx += 256) sWt[idx] = W_tag[idx];
  for (int idx = t; idx < 8192; idx += 256) sWc[idx] = W_comb[idx];

  float bsum = b_ih[t] + b_hh[t];
  ws[OFF_BIASS + t] = bsum;
  {
    float acc = bsum;
    for (int k = 0; k < 64; k++) acc = fmaf(W_ih[t*64 + k], lstm_init[k], acc);
    sg[t] = acc;
  }
  __syncthreads();

  if (t < 64){
    float ii = sigmf(sg[t]);
    float gg = tanhfast(sg[128 + t]);
    float oo = sigmf(sg[192 + t]);
    float c = ii * gg;
    float h = oo * tanhfast(c);
    sh1[t] = h;
    ws[OFF_H1C1 + t] = h;
    ws[OFF_H1C1 + 64 + t] = c;
  }
  __syncthreads();

  {
    float acc = bsum;
    for (int k = 0; k < 64; k++) acc = fmaf(W_hh[t*64 + k], sh1[k], acc);
    ws[OFF_BIAS2 + t] = acc;
  }
  for (int idx = t; idx < 26*64; idx += 256){
    int jj = idx / 26, v = idx - jj*26;
    float acc = b_comb[jj];
    for (int e = 0; e < 64; e++) acc = fmaf(sWc[jj*128 + 64 + e], emb[v*64 + e], acc);
    sceT[jj*32 + v] = acc;
  }
  for (int idx = t; idx < 4096; idx += 256){
    int jj = idx >> 6, kk = idx & 63;
    float acc = 0.f;
    for (int m = 0; m < 64; m++) acc = fmaf(sWt[jj*64 + m], sWc[m*128 + kk], acc);
    sM[idx] = acc;
    ws[OFF_M + idx] = acc;
  }
  __syncthreads();
  for (int idx = t; idx < 26*64; idx += 256){
    int jj = idx / 26, v = idx - jj*26;
    float acc = b_tag[jj];
    for (int k = 0; k < 64; k++) acc = fmaf(sWt[jj*64 + k], sceT[k*32 + v], acc);
    ws[OFF_TAGE2 + v*64 + jj] = acc;
    ste[v*64 + jj] = acc;
  }
  if (t < 64){
    float acc = 0.f;
    for (int k = 0; k < 64; k++) acc = fmaf(sM[t*64 + k], sh1[k], acc);
    sth[t] = acc;
  }
  __syncthreads();
  int w = t >> 6, j = t & 63;
  for (int v = w; v < 26; v += 4){
    float tag = sth[j] + ste[v*64 + j];
    ws[OFF_MEMO18 + v*64 + j] = logsoftmax64(tag);
  }
}

// ---------------- the cooperative everything-kernel ----------------
__global__ __launch_bounds__(512, 2) void k_main(
    const int* __restrict__ ids,
    const float* __restrict__ W_ih, const float* __restrict__ W_hh,
    float* __restrict__ ws, float* __restrict__ out)
{
  // fp16 weight staging: for k-pair kp, slot s=(j+kp)&63:
  //   sWi4[kp*64+s] = 4 gates x half2(W[g*64+j][2kp], W[g*64+j][2kp+1])
  // reads are 16B/lane contiguous across j -> conflict-free b128.
  __shared__ uint4 sWi4[2048];   // 32 KB
  __shared__ uint4 sWh4[2048];   // 32 KB
  __shared__ u32   sMp[2048];    //  8 KB   total 72 KB -> 2 blocks/CU
  u32* wsu = (u32*)ws;

  for (int idx = threadIdx.x; idx < 2048; idx += blockDim.x){
    int kp = idx >> 6, j = idx & 63;
    int slot = kp*64 + ((j + kp) & 63);
    uint4 wi, wh;
    wi.x = pk_rn(W_ih[(      j)*64 + 2*kp], W_ih[(      j)*64 + 2*kp + 1]);
    wi.y = pk_rn(W_ih[( 64 + j)*64 + 2*kp], W_ih[( 64 + j)*64 + 2*kp + 1]);
    wi.z = pk_rn(W_ih[(128 + j)*64 + 2*kp], W_ih[(128 + j)*64 + 2*kp + 1]);
    wi.w = pk_rn(W_ih[(192 + j)*64 + 2*kp], W_ih[(192 + j)*64 + 2*kp + 1]);
    wh.x = pk_rn(W_hh[(      j)*64 + 2*kp], W_hh[(      j)*64 + 2*kp + 1]);
    wh.y = pk_rn(W_hh[( 64 + j)*64 + 2*kp], W_hh[( 64 + j)*64 + 2*kp + 1]);
    wh.z = pk_rn(W_hh[(128 + j)*64 + 2*kp], W_hh[(128 + j)*64 + 2*kp + 1]);
    wh.w = pk_rn(W_hh[(192 + j)*64 + 2*kp], W_hh[(192 + j)*64 + 2*kp + 1]);
    sWi4[slot] = wi;
    sWh4[slot] = wh;
    sMp[slot]  = pk_rn(ws[OFF_M + j*64 + 2*kp], ws[OFF_M + j*64 + 2*kp + 1]);
  }
  __syncthreads();

  cg::grid_group grid = cg::this_grid();
  int wv = threadIdx.x >> 6, j = threadIdx.x & 63;
  int nw = gridDim.x * 8;
  int gw = blockIdx.x * 8 + wv;
  int j31 = j & 31;

  float c1  = ws[OFF_H1C1 + 64 + j];
  float b20 = ws[OFF_BIAS2 + j],       b21 = ws[OFF_BIAS2 + 64 + j];
  float b22 = ws[OFF_BIAS2 + 128 + j], b23 = ws[OFF_BIAS2 + 192 + j];
  float bs0 = ws[OFF_BIASS + j],       bs1 = ws[OFF_BIASS + 64 + j];
  float bs2 = ws[OFF_BIASS + 128 + j], bs3 = ws[OFF_BIASS + 192 + j];

  // ---- phase A: memo17 over 676 (lid,rid) pairs, 1 node/wave ----
  if (gw < 676){
    int lid = gw / 26, rid = gw - lid*26;
    u32 LP[1] = { packpair(ws[OFF_MEMO18 + lid*64 + j]) };
    u32 RP[1] = { packpair(ws[OFF_MEMO18 + rid*64 + j]) };
    float A0[1] = {b20}, A1[1] = {b21}, A2[1] = {b22}, A3[1] = {b23};
    dotW<1,1>(sWi4, LP, A0, A1, A2, A3, j);
    float c2 = sigmf(A1[0])*c1 + sigmf(A0[0])*tanhfast(A2[0]);
    float h2 = sigmf(A3[0])*tanhfast(c2);
    u32 HP[1] = { packpair(h2) };
    A0[0] = bs0; A1[0] = bs1; A2[0] = bs2; A3[0] = bs3;
    dotW<1,1>(sWi4, RP, A0, A1, A2, A3, j);
    dotW<1,1>(sWh4, HP, A0, A1, A2, A3, j);
    float c3 = sigmf(A1[0])*c2 + sigmf(A0[0])*tanhfast(A2[0]);
    float h3 = sigmf(A3[0])*tanhfast(c3);
    u32 H3P[1] = { packpair(h3) };
    float TH[1] = {0.f};
    dotM<1,1>(sMp, H3P, TH, j);
    for (int iid = 0; iid < 26; iid++){
      float tag = TH[0] + ws[OFF_TAGE2 + iid*64 + j];
      u32 pk = packpair(logsoftmax64(tag));
      if (!(j & 1)) wsu[OFF_M17P + (gw*26 + iid)*32 + (j >> 1)] = pk;
    }
  }
  grid.sync();

  // ---- phase B: h2/c2 tables over 17576 keys, 8 keys/wave ----
  for (int key0 = gw*8; key0 < 17576; key0 += nw*8){
    u32 XP[8]; float A0[8], A1[8], A2[8], A3[8];
    #pragma unroll
    for (int t = 0; t < 8; t++){
      int kc = key0 + t; if (kc > 17575) kc = 17575;
      XP[t] = wsu[OFF_M17P + kc*32 + j31];
      A0[t] = b20; A1[t] = b21; A2[t] = b22; A3[t] = b23;
    }
    dotW<8,0>(sWi4, XP, A0, A1, A2, A3, j);
    #pragma unroll
    for (int t = 0; t < 8; t++){
      int key = key0 + t;
      float c2 = sigmf(A1[t])*c1 + sigmf(A0[t])*tanhfast(A2[t]);
      float h2 = sigmf(A3[t])*tanhfast(c2);
      u32 pk = packpair(h2);
      if (key < 17576){
        ws[OFF_C2T + key*64 + j] = c2;
        if (!(j & 1)) wsu[OFF_H2P + key*32 + (j >> 1)] = pk;
      }
    }
  }
  grid.sync();

  // ---- phase C: level 16 (65536 nodes): gather h2/c2/R by key, step 3 ----
  for (int i0 = gw*8; i0 < 65536; i0 += nw*8){
    u32 RP[8], HP[8]; float C2v[8], A0[8], A1[8], A2[8], A3[8]; int idv[8];
    #pragma unroll
    for (int t = 0; t < 8; t++){
      int i = i0 + t;
      int m0 = 2*i, m1 = 2*i + 1;
      int kL = (ids[262143 + 2*m0]*26 + ids[262143 + 2*m0 + 1])*26 + ids[131071 + m0];
      int kR = (ids[262143 + 2*m1]*26 + ids[262143 + 2*m1 + 1])*26 + ids[131071 + m1];
      idv[t] = ids[65535 + i];
      RP[t]  = wsu[OFF_M17P + kR*32 + j31];
      HP[t]  = wsu[OFF_H2P  + kL*32 + j31];
      C2v[t] = ws[OFF_C2T + kL*64 + j];
      A0[t] = bs0; A1[t] = bs1; A2[t] = bs2; A3[t] = bs3;
    }
    dotW<8,0>(sWi4, RP, A0, A1, A2, A3, j);
    dotW<8,0>(sWh4, HP, A0, A1, A2, A3, j);
    u32 H3P[8];
    #pragma unroll
    for (int t = 0; t < 8; t++){
      float c3 = sigmf(A1[t])*C2v[t] + sigmf(A0[t])*tanhfast(A2[t]);
      H3P[t] = packpair(sigmf(A3[t])*tanhfast(c3));
    }
    float TH[8] = {0.f,0.f,0.f,0.f,0.f,0.f,0.f,0.f};
    dotM<8,1>(sMp, H3P, TH, j);
    #pragma unroll
    for (int t = 0; t < 8; t++){
      float tag = TH[t] + ws[OFF_TAGE2 + idv[t]*64 + j];
      u32 pk = packpair(logsoftmax64(tag));
      if (!(j & 1)) wsu[OFF_BUFA + (i0 + t)*32 + (j >> 1)] = pk;
    }
  }
  grid.sync();

  // ---- phase D: levels 15..0; levels <=6 run in block 0 only ----
  for (int l = 15; l >= 0; --l){
    int B = 1 << l;
    bool tail = (B <= 64);
    if (tail && blockIdx.x != 0) return;
    const u32* prevp = wsu + ((l & 1) ? OFF_BUFA : OFF_BUFB);
    u32*       curp  = wsu + ((l & 1) ? OFF_BUFB : OFF_BUFA);
    int start  = tail ? wv*8 : gw*8;
    int stride = tail ? 64   : nw*8;

    for (int i0 = start; i0 < B; i0 += stride){
      u32 LP[8], RP[8]; float A0[8], A1[8], A2[8], A3[8];
      #pragma unroll
      for (int t = 0; t < 8; t++){
        int i = i0 + t; int ic = (i < B) ? i : 0;
        LP[t] = prevp[(2*ic)*32 + j31];
        RP[t] = prevp[(2*ic + 1)*32 + j31];
        A0[t] = b20; A1[t] = b21; A2[t] = b22; A3[t] = b23;
      }
      dotW<8,0>(sWi4, LP, A0, A1, A2, A3, j);
      float C2v[8]; u32 HP[8];
      #pragma unroll
      for (int t = 0; t < 8; t++){
        float c2 = sigmf(A1[t])*c1 + sigmf(A0[t])*tanhfast(A2[t]);
        float h2 = sigmf(A3[t])*tanhfast(c2);
        C2v[t] = c2; HP[t] = packpair(h2);
        A0[t] = bs0; A1[t] = bs1; A2[t] = bs2; A3[t] = bs3;
      }
      dotW<8,0>(sWi4, RP, A0, A1, A2, A3, j);
      dotW<8,1>(sWh4, HP, A0, A1, A2, A3, j);
      u32 H3P[8];
      #pragma unroll
      for (int t = 0; t < 8; t++){
        float c3 = sigmf(A1[t])*C2v[t] + sigmf(A0[t])*tanhfast(A2[t]);
        H3P[t] = packpair(sigmf(A3[t])*tanhfast(c3));
      }
      float TH[8] = {0.f,0.f,0.f,0.f,0.f,0.f,0.f,0.f};
      dotM<8,1>(sMp, H3P, TH, j);
      #pragma unroll
      for (int t = 0; t < 8; t++){
        int i = i0 + t; bool ok = (i < B);
        int id = ids[(B - 1) + (ok ? i : 0)];
        float tag = TH[t] + ws[OFF_TAGE2 + id*64 + j];
        float v = logsoftmax64(tag);
        u32 pk = packpair(v);
        if (l == 0){
          if (ok) out[j] = v;            // root: fp32 log-probs to d_out
        } else if (ok && !(j & 1)){
          curp[i*32 + (j >> 1)] = pk;
        }
      }
    }
    if (tail) __syncthreads(); else grid.sync();
  }
}

extern "C" void kernel_launch(void* const* d_in, const int* in_sizes, int n_in,
                              void* d_out, int out_size, void* d_ws, size_t ws_size,
                              hipStream_t stream)
{
  (void)in_sizes; (void)n_in; (void)out_size; (void)ws_size;
  const int*   ids    = (const int*)  d_in[0];
  const float* emb    = (const float*)d_in[1];
  const float* W_ih   = (const float*)d_in[2];
  const float* W_hh   = (const float*)d_in[3];
  const float* b_ih   = (const float*)d_in[4];
  const float* b_hh   = (const float*)d_in[5];
  const float* W_comb = (const float*)d_in[6];
  const float* b_comb = (const float*)d_in[7];
  const float* W_tag  = (const float*)d_in[8];
  const float* b_tag  = (const float*)d_in[9];
  const float* linit  = (const float*)d_in[10];
  float* ws  = (float*)d_ws;
  float* out = (float*)d_out;

  k_pre<<<1, 256, 0, stream>>>(emb, W_ih, W_hh, b_ih, b_hh,
                               W_comb, b_comb, W_tag, b_tag, linit, ws);

  int maxb = 1;
  if (hipOccupancyMaxActiveBlocksPerMultiprocessor(&maxb, (const void*)k_main,
                                                   512, 0) != hipSuccess || maxb < 1)
    maxb = 1;
  int grid = maxb * 256; if (grid > 512) grid = 512;

  void* ka[5];
  ka[0] = (void*)&ids;  ka[1] = (void*)&W_ih; ka[2] = (void*)&W_hh;
  ka[3] = (void*)&ws;   ka[4] = (void*)&out;
  (void)hipLaunchCooperativeKernel((const void*)k_main, dim3(grid), dim3(512),
                                   ka, 0, stream);
}